// Round 10
// baseline (297.306 us; speedup 1.0000x reference)
//
#include <hip/hip_runtime.h>
#include <hip/hip_bf16.h>

// C[m][o] = sum_i x[m][i] * ternary[o][i] * scales[o*32 + i/128]
// M=8192, N=4096, K=4096. Fused prepass to bf16 (x cvt + W dequant) in d_ws,
// then 256x256 8-phase bf16 NT-GEMM, R6 stage/wait ledger, 32x32x16 MFMA.
// R10: LDS subtile = 32 rows x 16 k (1KiB), [rowTile32][kk] indexing -> each
// frag ds_read_b128 instr covers one full subtile bijectively (R9's pattern
// half-covered two subtiles -> 2.5e7 bank conflicts -> +31us, model-exact).
// Read XOR (r&4)<<2 gives every 8-lane group 8 distinct bank-quads; staging
// keeps linear gload_lds dest with the inverse involution folded into the
// per-lane global source (row l>>1, k8 = ((l&1)^((l>>3)&1))*8).

#define Msz 8192
#define Nsz 4096
#define Ksz 4096

typedef __attribute__((ext_vector_type(8))) short short8;
typedef __attribute__((ext_vector_type(16))) float f32x16;
typedef __attribute__((ext_vector_type(4))) int int4v;
typedef __attribute__((ext_vector_type(4))) float float4v;
typedef __attribute__((ext_vector_type(8))) unsigned short ushort8;

static __device__ __forceinline__ unsigned short f2bf(float f) {
    unsigned u = __builtin_bit_cast(unsigned, f);
    u += 0x7fffu + ((u >> 16) & 1u);
    return (unsigned short)(u >> 16);
}

// ---------------- fused prepass: blocks [0,2048) cvt x ; [2048,3072) dequant W ----------------
__global__ void prep(const float* __restrict__ x, const int* __restrict__ t,
                     const float* __restrict__ s,
                     unsigned short* __restrict__ ox, unsigned short* __restrict__ ow) {
    if (blockIdx.x < 2048) {
        int i = blockIdx.x * 256 + threadIdx.x;
        for (; i < Msz * Ksz / 8; i += 2048 * 256) {
            const float4v* p = (const float4v*)x + (size_t)i * 2;
            float4v a = p[0], b = p[1];
            ushort8 r;
            r[0] = f2bf(a[0]); r[1] = f2bf(a[1]); r[2] = f2bf(a[2]); r[3] = f2bf(a[3]);
            r[4] = f2bf(b[0]); r[5] = f2bf(b[1]); r[6] = f2bf(b[2]); r[7] = f2bf(b[3]);
            *((ushort8*)ox + i) = r;
        }
    } else {
        int i = (blockIdx.x - 2048) * 256 + threadIdx.x;
        for (; i < Nsz * Ksz / 8; i += 1024 * 256) {
            float sc = s[i >> 4];  // 8-elem chunk stays inside one 128-group
            const int4v* p = (const int4v*)t + (size_t)i * 2;
            int4v a = p[0], b = p[1];
            ushort8 r;
            r[0] = f2bf((float)a[0] * sc); r[1] = f2bf((float)a[1] * sc);
            r[2] = f2bf((float)a[2] * sc); r[3] = f2bf((float)a[3] * sc);
            r[4] = f2bf((float)b[0] * sc); r[5] = f2bf((float)b[1] * sc);
            r[6] = f2bf((float)b[2] * sc); r[7] = f2bf((float)b[3] * sc);
            *((ushort8*)ow + i) = r;
        }
    }
}

// ---------------- main GEMM ----------------
// 8 waves (2M x 4N). Wave (wr,wc): 4 rowfrags f of 32 rows at global rowTile32
// rt = f*2+wr (rt 0-3 = A-half0, 4-7 = half1 -> f's half = f>>1, R6 quadrant map).
// Cols: 2 colfrags n at ct = wc*2+n. LDS per buf: A 32K = [rt 0..7][kk 0..3]
// 1KiB subtiles (32 rows x 16 k), B 32K same by ct. byte = rt*4096 + kk*1024 +
// ((r*32 + hi*16) ^ ((r&4)<<2)), r=lane&31, hi=lane>>5.

#define READ_B32(b) {                                                            \
    _Pragma("unroll") for (int n = 0; n < 2; ++n)                                \
    _Pragma("unroll") for (int kk = 0; kk < 4; ++kk)                             \
      bf[n][kk] = *(const short8*)(L + (b)*65536 + 32768                         \
        + (((wc)*2+n)<<12) + (kk<<10) + laneB); }

#define READ_A32(b, f) {                                                         \
    _Pragma("unroll") for (int kk = 0; kk < 4; ++kk)                             \
      af[kk] = *(const short8*)(L + (b)*65536                                    \
        + (((f)*2+wr)<<12) + (kk<<10) + laneB); }

#define MFMAS32(f) {                                                             \
    _Pragma("unroll") for (int kk = 0; kk < 4; ++kk)                             \
    _Pragma("unroll") for (int n = 0; n < 2; ++n)                                \
      acc[f][n] = __builtin_amdgcn_mfma_f32_32x32x16_bf16(af[kk], bf[n][kk], acc[f][n], 0, 0, 0); }

// Stage one M-half (128 rows x K=64 = 16KB = 16 subtiles) at K-tile T into
// BOFF+MOFF+H*16384. Wave wid, load j covers subtile j*8+wid (rt4=j*2+(wid>>2),
// kk=wid&3) — per-lane/wid source offsets folded into pAb/pBb.
#define STAGE_H(PM, MOFF, BOFF, T, H) {                                          \
    _Pragma("unroll") for (int j = 0; j < 2; ++j)                                \
      __builtin_amdgcn_global_load_lds(                                          \
        (const __attribute__((address_space(1))) void*)(PM + (size_t)((H)*128 + j*64)*Ksz + (T)*64), \
        (__attribute__((address_space(3))) void*)(L + (BOFF) + (MOFF) + (H)*16384 + j*8192 + dOff), \
        16, 0, 0); }

#define WAITV8  asm volatile("s_waitcnt vmcnt(8)"  ::: "memory");
#define WAITV10 asm volatile("s_waitcnt vmcnt(10)" ::: "memory");

#define PHASE(READS, MF, STG, WV)                                                \
    READS;                                                                       \
    STG;                                                                         \
    __builtin_amdgcn_sched_barrier(0);                                           \
    __builtin_amdgcn_s_barrier();                                                \
    asm volatile("s_waitcnt lgkmcnt(0)" ::: "memory");                           \
    __builtin_amdgcn_sched_barrier(0);                                           \
    __builtin_amdgcn_s_setprio(1);                                               \
    MF;                                                                          \
    __builtin_amdgcn_s_setprio(0);                                               \
    WV;                                                                          \
    __builtin_amdgcn_sched_barrier(0);                                           \
    __builtin_amdgcn_s_barrier();                                                \
    __builtin_amdgcn_sched_barrier(0);

__global__ __launch_bounds__(512, 2) void gemm_8p(const unsigned short* __restrict__ A,
                                                  const unsigned short* __restrict__ B,
                                                  float* __restrict__ C) {
    __shared__ __align__(16) unsigned char L[131072]; // 128 KiB

    const int tid  = threadIdx.x;
    const int lane = tid & 63;
    const int wid  = tid >> 6;
    const int wr   = wid >> 2;   // 0..1
    const int wc   = wid & 3;    // 0..3
    const int rowBase = blockIdx.y * 256;
    const int colBase = blockIdx.x * 256;

    // frag reader: byte within 1KiB subtile (bijective per instr, bank-spread)
    const int laneB = (((lane & 31) * 32) + ((lane >> 5) * 16)) ^ ((lane & 4) << 2);
    // stager: lane l -> row l>>1, k8 = ((l&1)^((l>>3)&1))*8 (inverse involution);
    // wave wid -> row-block (wid>>2)*32, k16-slot (wid&3)*16
    const int k8   = ((lane & 1) ^ ((lane >> 3) & 1)) * 8;
    const int dOff = wid * 1024;

    const unsigned short* pAb = A + (size_t)(rowBase + (wid >> 2) * 32 + (lane >> 1)) * Ksz
                                  + (wid & 3) * 16 + k8;
    const unsigned short* pBb = B + (size_t)(colBase + (wid >> 2) * 32 + (lane >> 1)) * Ksz
                                  + (wid & 3) * 16 + k8;

    f32x16 acc[4][2] = {};
    short8 af[4], bf[2][4];

    // ---- prologue (R6 ledger): t0.{B.h0,A.h0,B.h1,A.h1} + t1.{B.h0,A.h1,B.h1} ----
    STAGE_H(pBb, 32768, 0,     0, 0);
    STAGE_H(pAb, 0,     0,     0, 0);
    STAGE_H(pBb, 32768, 0,     0, 1);
    STAGE_H(pAb, 0,     0,     0, 1);
    STAGE_H(pBb, 32768, 65536, 1, 0);
    STAGE_H(pAb, 0,     65536, 1, 1);
    STAGE_H(pBb, 32768, 65536, 1, 1);
    WAITV8                       // retires t0.{B.h0,A.h0,B.h1}; 8 stay in flight
    __builtin_amdgcn_sched_barrier(0);
    __builtin_amdgcn_s_barrier();
    __builtin_amdgcn_sched_barrier(0);

    for (int i = 0; i < 32; ++i) {
        const int t1 = 2 * i + 1;
        const int t2 = (i < 31) ? 2 * i + 2 : 62;  // clamp: last-iter stages are
        const int t3 = (i < 31) ? 2 * i + 3 : 62;  // dead writes into freed regions

        // tile t=2i in buf0: rowfrags 0,1 (A-half0) then 2,3 (A-half1);
        // tile t+1 in buf1: reversed 2,3 then 0,1. Stage slots/waits = R6 ledger.
        PHASE({ READ_B32(0); READ_A32(0, 0); }, MFMAS32(0), STAGE_H(pAb, 0,     65536, t1, 0), )        // P1
        PHASE(READ_A32(0, 1),                   MFMAS32(1), STAGE_H(pBb, 32768, 0,     t2, 0), WAITV10) // P2
        PHASE(READ_A32(0, 2),                   MFMAS32(2), STAGE_H(pAb, 0,     0,     t2, 0), )        // P3
        PHASE(READ_A32(0, 3),                   MFMAS32(3), STAGE_H(pBb, 32768, 0,     t2, 1), WAITV8)  // P4
        PHASE({ READ_B32(1); READ_A32(1, 2); }, MFMAS32(2), STAGE_H(pAb, 0,     0,     t2, 1), )        // P5
        PHASE(READ_A32(1, 3),                   MFMAS32(3), STAGE_H(pBb, 32768, 65536, t3, 0), WAITV10) // P6
        PHASE(READ_A32(1, 0),                   MFMAS32(0), STAGE_H(pAb, 0,     65536, t3, 1), )        // P7
        PHASE(READ_A32(1, 1),                   MFMAS32(1), STAGE_H(pBb, 32768, 65536, t3, 1), WAITV8)  // P8
    }

    // drain outstanding gload_lds before LDS teardown / endpgm
    asm volatile("s_waitcnt vmcnt(0)" ::: "memory");

    // epilogue: 32x32 C/D layout (m74/m101, R9-verified): col = lane&31,
    // row = (reg&3) + 8*(reg>>2) + 4*((lane>>5)&1)
    const int hi = (lane >> 5) & 1;
    const int ccol = colBase + wc * 64 + (lane & 31);
#pragma unroll
    for (int f = 0; f < 4; ++f)
#pragma unroll
        for (int n = 0; n < 2; ++n) {
            const int r0 = rowBase + (f * 2 + wr) * 32 + 4 * hi;
            float* cp = C + (size_t)r0 * Nsz + ccol + n * 32;
#pragma unroll
            for (int g = 0; g < 4; ++g)
#pragma unroll
                for (int j = 0; j < 4; ++j)
                    cp[(size_t)(g * 8 + j) * Nsz] = acc[f][n][g * 4 + j];
        }
}

// ---------------- fallback (ws too small): exact fp32, slow but correct ----------------
__global__ void gemm_naive(const float* __restrict__ x, const int* __restrict__ t,
                           const float* __restrict__ s, float* __restrict__ C) {
    size_t o = (size_t)blockIdx.x * blockDim.x + threadIdx.x;
    if (o >= (size_t)Msz * Nsz) return;
    int m = (int)(o / Nsz), n = (int)(o % Nsz);
    float acc = 0.f;
    for (int g = 0; g < Ksz / 128; ++g) {
        float sc = s[n * (Ksz / 128) + g];
        float p = 0.f;
        const float* xp = x + (size_t)m * Ksz + g * 128;
        const int* tp = t + (size_t)n * Ksz + g * 128;
        for (int k = 0; k < 128; ++k) p += xp[k] * (float)tp[k];
        acc += sc * p;
    }
    C[o] = acc;
}

extern "C" void kernel_launch(void* const* d_in, const int* in_sizes, int n_in,
                              void* d_out, int out_size, void* d_ws, size_t ws_size,
                              hipStream_t stream) {
    const float* x      = (const float*)d_in[0];
    const int*   tern   = (const int*)d_in[1];
    const float* scales = (const float*)d_in[2];
    float* out = (float*)d_out;

    const size_t aBytes = (size_t)Msz * Ksz * 2; // 64 MiB
    const size_t bBytes = (size_t)Nsz * Ksz * 2; // 32 MiB

    if (ws_size >= aBytes + bBytes) {
        unsigned short* Abf = (unsigned short*)d_ws;
        unsigned short* Bbf = (unsigned short*)((char*)d_ws + aBytes);
        prep<<<3072, 256, 0, stream>>>(x, tern, scales, Abf, Bbf);
        dim3 grid(Nsz / 256, Msz / 256);
        gemm_8p<<<grid, 512, 0, stream>>>(Abf, Bbf, out);
    } else {
        gemm_naive<<<(int)(((size_t)Msz * Nsz + 255) / 256), 256, 0, stream>>>(x, tern, scales, out);
    }
}

// Round 11
// 277.139 us; speedup vs baseline: 1.0728x; 1.0728x over previous
//
#include <hip/hip_runtime.h>
#include <hip/hip_bf16.h>

// C[m][o] = sum_i x[m][i] * ternary[o][i] * scales[o*32 + i/128]
// M=8192, N=4096, K=4096. Fused prepass to bf16 (x cvt + W dequant) in d_ws,
// then 256x256 8-phase bf16 NT-GEMM (R6 stage/wait ledger, 16x16x32 MFMA)
// + fragment-register double-buffering (R8 schedule: MFMA(p) consumes frags
// read at p-1, counted lgkmcnt gates).
// R11 = R8 with amdgpu_waves_per_eu(2,2): R8's allocator chose 128 VGPR
// (targeting impossible 4 waves/EU; LDS=128K caps 1 block/CU) and spilled
// ~224 live values -> +23MB scratch WRITE_SIZE. Pin 2 waves/EU -> 256 budget.

#define Msz 8192
#define Nsz 4096
#define Ksz 4096

typedef __attribute__((ext_vector_type(8))) short short8;
typedef __attribute__((ext_vector_type(4))) float f32x4;
typedef __attribute__((ext_vector_type(4))) int int4v;
typedef __attribute__((ext_vector_type(4))) float float4v;
typedef __attribute__((ext_vector_type(8))) unsigned short ushort8;

static __device__ __forceinline__ unsigned short f2bf(float f) {
    unsigned u = __builtin_bit_cast(unsigned, f);
    u += 0x7fffu + ((u >> 16) & 1u);
    return (unsigned short)(u >> 16);
}

// ---------------- fused prepass: blocks [0,2048) cvt x ; [2048,3072) dequant W ----------------
__global__ void prep(const float* __restrict__ x, const int* __restrict__ t,
                     const float* __restrict__ s,
                     unsigned short* __restrict__ ox, unsigned short* __restrict__ ow) {
    if (blockIdx.x < 2048) {
        int i = blockIdx.x * 256 + threadIdx.x;
        for (; i < Msz * Ksz / 8; i += 2048 * 256) {
            const float4v* p = (const float4v*)x + (size_t)i * 2;
            float4v a = p[0], b = p[1];
            ushort8 r;
            r[0] = f2bf(a[0]); r[1] = f2bf(a[1]); r[2] = f2bf(a[2]); r[3] = f2bf(a[3]);
            r[4] = f2bf(b[0]); r[5] = f2bf(b[1]); r[6] = f2bf(b[2]); r[7] = f2bf(b[3]);
            *((ushort8*)ox + i) = r;
        }
    } else {
        int i = (blockIdx.x - 2048) * 256 + threadIdx.x;
        for (; i < Nsz * Ksz / 8; i += 1024 * 256) {
            float sc = s[i >> 4];  // 8-elem chunk stays inside one 128-group
            const int4v* p = (const int4v*)t + (size_t)i * 2;
            int4v a = p[0], b = p[1];
            ushort8 r;
            r[0] = f2bf((float)a[0] * sc); r[1] = f2bf((float)a[1] * sc);
            r[2] = f2bf((float)a[2] * sc); r[3] = f2bf((float)a[3] * sc);
            r[4] = f2bf((float)b[0] * sc); r[5] = f2bf((float)b[1] * sc);
            r[6] = f2bf((float)b[2] * sc); r[7] = f2bf((float)b[3] * sc);
            *((ushort8*)ow + i) = r;
        }
    }
}

// ---------------- main GEMM ----------------
// 8 waves (2M x 4N). Per-wave 8 M-frags at rowTile = q*4 + wr*2 + m; quadrant q
// lies in A-half q>>1. LDS: 2 buf x {A 32K, B 32K}, 1KiB subtiles (16r x 32k),
// XOR-swizzled (verified). Loop body = phases [P2..P8,P1'] of the R6 schedule;
// MFMA(p) consumes frags read at p-1 (alternating afE/afO, bfrE/bfrO).

#define READ_B_TO(S, b) {                                                        \
    _Pragma("unroll") for (int n = 0; n < 4; ++n)                                \
    _Pragma("unroll") for (int ks = 0; ks < 2; ++ks)                             \
      S[n][ks] = *(const short8*)(L + (b)*65536 + 32768 + ((((wc)*4+n)*2+ks)<<10) + laneA); }

#define READ_A_TO(S, b, q) {                                                     \
    _Pragma("unroll") for (int m = 0; m < 2; ++m)                                \
    _Pragma("unroll") for (int ks = 0; ks < 2; ++ks)                             \
      S[m][ks] = *(const short8*)(L + (b)*65536 + ((((q)*4+(wr)*2+m)*2+ks)<<10) + laneA); }

#define MFMAS_X(q, AF, BF) {                                                     \
    _Pragma("unroll") for (int m = 0; m < 2; ++m)                                \
    _Pragma("unroll") for (int n = 0; n < 4; ++n) {                              \
      acc[(q)*2+m][n] = __builtin_amdgcn_mfma_f32_16x16x32_bf16(AF[m][0], BF[n][0], acc[(q)*2+m][n], 0, 0, 0); \
      acc[(q)*2+m][n] = __builtin_amdgcn_mfma_f32_16x16x32_bf16(AF[m][1], BF[n][1], acc[(q)*2+m][n], 0, 0, 0); } }

// Stage one M-half (128 rows x K=64 = 16KB) at K-tile T into BOFF+MOFF+H*16384.
#define STAGE_H(PM, MOFF, BOFF, T, H) {                                          \
    _Pragma("unroll") for (int j = 0; j < 2; ++j)                                \
      __builtin_amdgcn_global_load_lds(                                          \
        (const __attribute__((address_space(1))) void*)(PM + (size_t)((H)*128 + j*64)*Ksz + (T)*64), \
        (__attribute__((address_space(3))) void*)(L + (BOFF) + (MOFF) + (H)*16384 + j*8192 + dOff), \
        16, 0, 0); }

#define WAITV8  asm volatile("s_waitcnt vmcnt(8)"  ::: "memory");
#define WAITV10 asm volatile("s_waitcnt vmcnt(10)" ::: "memory");
#define LG4  asm volatile("s_waitcnt lgkmcnt(4)"  ::: "memory");
#define LG12 asm volatile("s_waitcnt lgkmcnt(12)" ::: "memory");

#define PHASEP(READS, MF, STG, LG, WV)                                           \
    READS;                                                                       \
    STG;                                                                         \
    __builtin_amdgcn_sched_barrier(0);                                           \
    __builtin_amdgcn_s_barrier();                                                \
    LG;                                                                          \
    __builtin_amdgcn_sched_barrier(0);                                           \
    __builtin_amdgcn_s_setprio(1);                                               \
    MF;                                                                          \
    __builtin_amdgcn_s_setprio(0);                                               \
    WV;                                                                          \
    __builtin_amdgcn_sched_barrier(0);                                           \
    __builtin_amdgcn_s_barrier();                                                \
    __builtin_amdgcn_sched_barrier(0);

__global__ __attribute__((amdgpu_flat_work_group_size(512, 512), amdgpu_waves_per_eu(2, 2)))
void gemm_8p(const unsigned short* __restrict__ A,
             const unsigned short* __restrict__ B,
             float* __restrict__ C) {
    __shared__ __align__(16) unsigned char L[131072]; // 128 KiB

    const int tid  = threadIdx.x;
    const int lane = tid & 63;
    const int wid  = tid >> 6;
    const int wr   = wid >> 2;   // 0..1
    const int wc   = wid & 3;    // 0..3
    const int rowBase = blockIdx.y * 256;
    const int colBase = blockIdx.x * 256;

    // reader swizzled per-lane byte offset within a 1KiB subtile
    const int laneA = (((lane & 15) * 64) + ((lane >> 4) * 16)) ^ (((lane >> 3) & 1) << 5);
    // stager inverse-swizzled per-lane source k-offset (verified involution)
    const int kloc = (lane & 1) * 8 + (((lane >> 1) ^ (lane >> 5)) & 1) * 16;
    const int r_st = lane >> 2;
    const int dOff = wid * 1024;

    const unsigned short* pAb = A + (size_t)(rowBase + (wid >> 1) * 16 + r_st) * Ksz + (wid & 1) * 32 + kloc;
    const unsigned short* pBb = B + (size_t)(colBase + (wid >> 1) * 16 + r_st) * Ksz + (wid & 1) * 32 + kloc;

    f32x4 acc[8][4] = {};
    short8 afE[2][2], afO[2][2], bfrE[4][2], bfrO[4][2];

    // ---- prologue: t0.{B.h0,A.h0,B.h1,A.h1} + t1.{B.h0,A.h1,B.h1} = 14 loads ----
    STAGE_H(pBb, 32768, 0,     0, 0);
    STAGE_H(pAb, 0,     0,     0, 0);
    STAGE_H(pBb, 32768, 0,     0, 1);
    STAGE_H(pAb, 0,     0,     0, 1);
    STAGE_H(pBb, 32768, 65536, 1, 0);
    STAGE_H(pAb, 0,     65536, 1, 1);
    STAGE_H(pBb, 32768, 65536, 1, 1);
    WAITV8                       // retires t0.{B.h0,A.h0,B.h1}; 8 stay in flight
    __builtin_amdgcn_sched_barrier(0);
    __builtin_amdgcn_s_barrier();
    __builtin_amdgcn_sched_barrier(0);

    // ---- peeled P1 (no MFMA): read B(t0)+A(t0,q0); stage t1.A.h0 ----
    READ_B_TO(bfrE, 0);
    READ_A_TO(afE, 0, 0);
    STAGE_H(pAb, 0, 65536, 1, 0);
    __builtin_amdgcn_sched_barrier(0);
    __builtin_amdgcn_s_barrier();
    __builtin_amdgcn_sched_barrier(0);

    for (int i = 0; i < 32; ++i) {
        const int t2 = (i < 31) ? 2 * i + 2 : 62;  // clamp: last-iter stages are
        const int t3 = (i < 31) ? 2 * i + 3 : 62;  // dead writes into freed regions

        // phases [P2..P8, P1'(next)] — reads/stages/waits = R6 ledger; MFMA(p)
        // consumes the set read at p-1.
        PHASEP(READ_A_TO(afO, 0, 1),                      MFMAS_X(0, afE, bfrE), STAGE_H(pBb, 32768, 0,     t2, 0), LG4,  WAITV10) // P2
        PHASEP(READ_A_TO(afE, 0, 2),                      MFMAS_X(1, afO, bfrE), STAGE_H(pAb, 0,     0,     t2, 0), LG4,  )        // P3
        PHASEP(READ_A_TO(afO, 0, 3),                      MFMAS_X(2, afE, bfrE), STAGE_H(pBb, 32768, 0,     t2, 1), LG4,  WAITV8)  // P4
        PHASEP({ READ_B_TO(bfrO, 1); READ_A_TO(afE, 1, 2); }, MFMAS_X(3, afO, bfrE), STAGE_H(pAb, 0,     0,     t2, 1), LG12, )        // P5
        PHASEP(READ_A_TO(afO, 1, 3),                      MFMAS_X(2, afE, bfrO), STAGE_H(pBb, 32768, 65536, t3, 0), LG4,  WAITV10) // P6
        PHASEP(READ_A_TO(afE, 1, 0),                      MFMAS_X(3, afO, bfrO), STAGE_H(pAb, 0,     65536, t3, 1), LG4,  )        // P7
        PHASEP(READ_A_TO(afO, 1, 1),                      MFMAS_X(0, afE, bfrO), STAGE_H(pBb, 32768, 65536, t3, 1), LG4,  WAITV8)  // P8
        PHASEP({ READ_B_TO(bfrE, 0); READ_A_TO(afE, 0, 0); }, MFMAS_X(1, afO, bfrO), STAGE_H(pAb, 0,     65536, t3, 0), LG12, )        // P1'
    }
    // loop closes the computation (iter 31's P1' does q1 of tile 63); the
    // trailing P1' reads are dead (stale data, regs never consumed).

    // drain outstanding gload_lds / ds_reads before LDS teardown / endpgm
    asm volatile("s_waitcnt vmcnt(0) lgkmcnt(0)" ::: "memory");

    // epilogue: frag (q,m) at rowTile q*4+wr*2+m; C/D: col=lane&15, row=(lane>>4)*4+j
    const int crl = (lane >> 4) * 4;
    const int ccol0 = colBase + wc * 64 + (lane & 15);
#pragma unroll
    for (int q = 0; q < 4; ++q)
#pragma unroll
        for (int m = 0; m < 2; ++m)
#pragma unroll
            for (int n = 0; n < 4; ++n) {
                const int row0 = rowBase + (q * 4 + wr * 2 + m) * 16 + crl;
                float* cp = C + (size_t)row0 * Nsz + ccol0 + n * 16;
#pragma unroll
                for (int j = 0; j < 4; ++j)
                    cp[(size_t)j * Nsz] = acc[q * 2 + m][n][j];
            }
}

// ---------------- fallback (ws too small): exact fp32, slow but correct ----------------
__global__ void gemm_naive(const float* __restrict__ x, const int* __restrict__ t,
                           const float* __restrict__ s, float* __restrict__ C) {
    size_t o = (size_t)blockIdx.x * blockDim.x + threadIdx.x;
    if (o >= (size_t)Msz * Nsz) return;
    int m = (int)(o / Nsz), n = (int)(o % Nsz);
    float acc = 0.f;
    for (int g = 0; g < Ksz / 128; ++g) {
        float sc = s[n * (Ksz / 128) + g];
        float p = 0.f;
        const float* xp = x + (size_t)m * Ksz + g * 128;
        const int* tp = t + (size_t)n * Ksz + g * 128;
        for (int k = 0; k < 128; ++k) p += xp[k] * (float)tp[k];
        acc += sc * p;
    }
    C[o] = acc;
}

extern "C" void kernel_launch(void* const* d_in, const int* in_sizes, int n_in,
                              void* d_out, int out_size, void* d_ws, size_t ws_size,
                              hipStream_t stream) {
    const float* x      = (const float*)d_in[0];
    const int*   tern   = (const int*)d_in[1];
    const float* scales = (const float*)d_in[2];
    float* out = (float*)d_out;

    const size_t aBytes = (size_t)Msz * Ksz * 2; // 64 MiB
    const size_t bBytes = (size_t)Nsz * Ksz * 2; // 32 MiB

    if (ws_size >= aBytes + bBytes) {
        unsigned short* Abf = (unsigned short*)d_ws;
        unsigned short* Bbf = (unsigned short*)((char*)d_ws + aBytes);
        prep<<<3072, 256, 0, stream>>>(x, tern, scales, Abf, Bbf);
        dim3 grid(Nsz / 256, Msz / 256);
        gemm_8p<<<grid, 512, 0, stream>>>(Abf, Bbf, out);
    } else {
        gemm_naive<<<(int)(((size_t)Msz * Nsz + 255) / 256), 256, 0, stream>>>(x, tern, scales, out);
    }
}

// Round 12
// 266.458 us; speedup vs baseline: 1.1158x; 1.0401x over previous
//
#include <hip/hip_runtime.h>
#include <hip/hip_bf16.h>

// C[m][o] = sum_i x[m][i] * ternary[o][i] * scales[o*32 + i/128]
// M=8192, N=4096, K=4096. Fused prepass to bf16 (x cvt + W dequant) in d_ws,
// then 256x256 8-phase bf16 NT-GEMM, R6 stage/wait ledger + 16x16x32 MFMA.
// R12: tail-hoisted ds_reads — phases P2,P3,P4,P6,P8 get their fragment
// reads issued in the PREVIOUS phase's tail (after MFMA, before the closing
// barrier), into the SAME registers (WAR resolves at MFMA issue; zero extra
// VGPR). Safe because those regions were published >=1 barrier earlier
// (publication audit in comments). P1/P5 (post-publication bursts) and P7
// (A.h0 first quadrant) keep reads at phase start.

#define Msz 8192
#define Nsz 4096
#define Ksz 4096

typedef __attribute__((ext_vector_type(8))) short short8;
typedef __attribute__((ext_vector_type(4))) float f32x4;
typedef __attribute__((ext_vector_type(4))) int int4v;
typedef __attribute__((ext_vector_type(4))) float float4v;
typedef __attribute__((ext_vector_type(8))) unsigned short ushort8;

static __device__ __forceinline__ unsigned short f2bf(float f) {
    unsigned u = __builtin_bit_cast(unsigned, f);
    u += 0x7fffu + ((u >> 16) & 1u);
    return (unsigned short)(u >> 16);
}

// ---------------- fused prepass: blocks [0,2048) cvt x ; [2048,3072) dequant W ----------------
__global__ void prep(const float* __restrict__ x, const int* __restrict__ t,
                     const float* __restrict__ s,
                     unsigned short* __restrict__ ox, unsigned short* __restrict__ ow) {
    if (blockIdx.x < 2048) {
        int i = blockIdx.x * 256 + threadIdx.x;
        for (; i < Msz * Ksz / 8; i += 2048 * 256) {
            const float4v* p = (const float4v*)x + (size_t)i * 2;
            float4v a = p[0], b = p[1];
            ushort8 r;
            r[0] = f2bf(a[0]); r[1] = f2bf(a[1]); r[2] = f2bf(a[2]); r[3] = f2bf(a[3]);
            r[4] = f2bf(b[0]); r[5] = f2bf(b[1]); r[6] = f2bf(b[2]); r[7] = f2bf(b[3]);
            *((ushort8*)ox + i) = r;
        }
    } else {
        int i = (blockIdx.x - 2048) * 256 + threadIdx.x;
        for (; i < Nsz * Ksz / 8; i += 1024 * 256) {
            float sc = s[i >> 4];  // 8-elem chunk stays inside one 128-group
            const int4v* p = (const int4v*)t + (size_t)i * 2;
            int4v a = p[0], b = p[1];
            ushort8 r;
            r[0] = f2bf((float)a[0] * sc); r[1] = f2bf((float)a[1] * sc);
            r[2] = f2bf((float)a[2] * sc); r[3] = f2bf((float)a[3] * sc);
            r[4] = f2bf((float)b[0] * sc); r[5] = f2bf((float)b[1] * sc);
            r[6] = f2bf((float)b[2] * sc); r[7] = f2bf((float)b[3] * sc);
            *((ushort8*)ow + i) = r;
        }
    }
}

// ---------------- main GEMM ----------------
// 8 waves (2M x 4N). Per-wave 8 M-frags at rowTile = q*4 + wr*2 + m; quadrant q
// lies in A-half q>>1. LDS: 2 buf x {A 32K, B 32K}, 1KiB subtiles (16r x 32k),
// XOR-swizzled (verified involution). Phase MFMA order: t in buf0 q0,q1,q2,q3;
// t' in buf1 q2,q3,q0,q1 (reversed). Stage slots + vmcnt waits = R6 ledger.
// Read placement (publication-audited):
//   P1 PRE : B(0)+A(0,q0)   [t published P8-bar prev]   P1 POST: A(0,q1)
//   P2 POST: A(0,q2)        P3 POST: A(0,q3)            P4 POST: none
//   P5 PRE : B(1)+A(1,q2)   [t' published P4-bar]       P5 POST: A(1,q3)
//   P6 POST: none           P7 PRE: A(1,q0) [A.h0 pub P6-bar]  P7 POST: A(1,q1)
//   P8 POST: none

#define READ_B(b) {                                                              \
    _Pragma("unroll") for (int n = 0; n < 4; ++n)                                \
    _Pragma("unroll") for (int ks = 0; ks < 2; ++ks)                             \
      bfr[n][ks] = *(const short8*)(L + (b)*65536 + 32768 + ((((wc)*4+n)*2+ks)<<10) + laneA); }

#define READ_A(b, q) {                                                           \
    _Pragma("unroll") for (int m = 0; m < 2; ++m)                                \
    _Pragma("unroll") for (int ks = 0; ks < 2; ++ks)                             \
      af[m][ks] = *(const short8*)(L + (b)*65536 + ((((q)*4+(wr)*2+m)*2+ks)<<10) + laneA); }

#define MFMAS(q) {                                                               \
    _Pragma("unroll") for (int m = 0; m < 2; ++m)                                \
    _Pragma("unroll") for (int n = 0; n < 4; ++n) {                              \
      acc[(q)*2+m][n] = __builtin_amdgcn_mfma_f32_16x16x32_bf16(af[m][0], bfr[n][0], acc[(q)*2+m][n], 0, 0, 0); \
      acc[(q)*2+m][n] = __builtin_amdgcn_mfma_f32_16x16x32_bf16(af[m][1], bfr[n][1], acc[(q)*2+m][n], 0, 0, 0); } }

// Stage one M-half (128 rows x K=64 = 16KB) at K-tile T into BOFF+MOFF+H*16384.
#define STAGE_H(PM, MOFF, BOFF, T, H) {                                          \
    _Pragma("unroll") for (int j = 0; j < 2; ++j)                                \
      __builtin_amdgcn_global_load_lds(                                          \
        (const __attribute__((address_space(1))) void*)(PM + (size_t)((H)*128 + j*64)*Ksz + (T)*64), \
        (__attribute__((address_space(3))) void*)(L + (BOFF) + (MOFF) + (H)*16384 + j*8192 + dOff), \
        16, 0, 0); }

#define WAITV8  asm volatile("s_waitcnt vmcnt(8)"  ::: "memory");
#define WAITV10 asm volatile("s_waitcnt vmcnt(10)" ::: "memory");

// PRE reads + stage -> bar -> lgkm0 -> MFMA -> POST reads (next phase) -> vm wait -> bar
#define PHASE2(PRE, STG, MF, POST, WV)                                           \
    PRE;                                                                         \
    STG;                                                                         \
    __builtin_amdgcn_sched_barrier(0);                                           \
    __builtin_amdgcn_s_barrier();                                                \
    asm volatile("s_waitcnt lgkmcnt(0)" ::: "memory");                           \
    __builtin_amdgcn_sched_barrier(0);                                           \
    __builtin_amdgcn_s_setprio(1);                                               \
    MF;                                                                          \
    __builtin_amdgcn_s_setprio(0);                                               \
    __builtin_amdgcn_sched_barrier(0);                                           \
    POST;                                                                        \
    WV;                                                                          \
    __builtin_amdgcn_sched_barrier(0);                                           \
    __builtin_amdgcn_s_barrier();                                                \
    __builtin_amdgcn_sched_barrier(0);

__global__ __launch_bounds__(512, 2) void gemm_8p(const unsigned short* __restrict__ A,
                                                  const unsigned short* __restrict__ B,
                                                  float* __restrict__ C) {
    __shared__ __align__(16) unsigned char L[131072]; // 128 KiB

    const int tid  = threadIdx.x;
    const int lane = tid & 63;
    const int wid  = tid >> 6;
    const int wr   = wid >> 2;   // 0..1
    const int wc   = wid & 3;    // 0..3
    const int rowBase = blockIdx.y * 256;
    const int colBase = blockIdx.x * 256;

    // reader swizzled per-lane byte offset within a 1KiB subtile
    const int laneA = (((lane & 15) * 64) + ((lane >> 4) * 16)) ^ (((lane >> 3) & 1) << 5);
    // stager inverse-swizzled per-lane source k-offset (verified involution)
    const int kloc = (lane & 1) * 8 + (((lane >> 1) ^ (lane >> 5)) & 1) * 16;
    const int r_st = lane >> 2;
    const int dOff = wid * 1024;

    const unsigned short* pAb = A + (size_t)(rowBase + (wid >> 1) * 16 + r_st) * Ksz + (wid & 1) * 32 + kloc;
    const unsigned short* pBb = B + (size_t)(colBase + (wid >> 1) * 16 + r_st) * Ksz + (wid & 1) * 32 + kloc;

    f32x4 acc[8][4] = {};
    short8 af[2][2], bfr[4][2];

    // ---- prologue (R6 ledger): t0.{B.h0,A.h0,B.h1,A.h1} + t1.{B.h0,A.h1,B.h1} ----
    STAGE_H(pBb, 32768, 0,     0, 0);
    STAGE_H(pAb, 0,     0,     0, 0);
    STAGE_H(pBb, 32768, 0,     0, 1);
    STAGE_H(pAb, 0,     0,     0, 1);
    STAGE_H(pBb, 32768, 65536, 1, 0);
    STAGE_H(pAb, 0,     65536, 1, 1);
    STAGE_H(pBb, 32768, 65536, 1, 1);
    WAITV8                       // retires t0.{B.h0,A.h0,B.h1}; 8 stay in flight
    __builtin_amdgcn_sched_barrier(0);
    __builtin_amdgcn_s_barrier();
    __builtin_amdgcn_sched_barrier(0);

    for (int i = 0; i < 32; ++i) {
        const int t1 = 2 * i + 1;
        const int t2 = (i < 31) ? 2 * i + 2 : 62;  // clamp: last-iter stages are
        const int t3 = (i < 31) ? 2 * i + 3 : 62;  // dead writes into freed regions

        PHASE2({ READ_B(0); READ_A(0, 0); }, STAGE_H(pAb, 0,     65536, t1, 0),
               MFMAS(0), READ_A(0, 1), )                                           // P1
        PHASE2(,                             STAGE_H(pBb, 32768, 0,     t2, 0),
               MFMAS(1), READ_A(0, 2), WAITV10)                                    // P2
        PHASE2(,                             STAGE_H(pAb, 0,     0,     t2, 0),
               MFMAS(2), READ_A(0, 3), )                                           // P3
        PHASE2(,                             STAGE_H(pBb, 32768, 0,     t2, 1),
               MFMAS(3), , WAITV8)                                                 // P4
        PHASE2({ READ_B(1); READ_A(1, 2); }, STAGE_H(pAb, 0,     0,     t2, 1),
               MFMAS(2), READ_A(1, 3), )                                           // P5
        PHASE2(,                             STAGE_H(pBb, 32768, 65536, t3, 0),
               MFMAS(3), , WAITV10)                                                // P6
        PHASE2(READ_A(1, 0),                 STAGE_H(pAb, 0,     65536, t3, 1),
               MFMAS(0), READ_A(1, 1), )                                           // P7
        PHASE2(,                             STAGE_H(pBb, 32768, 65536, t3, 1),
               MFMAS(1), , WAITV8)                                                 // P8
    }

    // drain outstanding gload_lds before LDS teardown / endpgm
    asm volatile("s_waitcnt vmcnt(0) lgkmcnt(0)" ::: "memory");

    // epilogue: frag (q,m) at rowTile q*4+wr*2+m; C/D: col=lane&15, row=(lane>>4)*4+j
    const int crl = (lane >> 4) * 4;
    const int ccol0 = colBase + wc * 64 + (lane & 15);
#pragma unroll
    for (int q = 0; q < 4; ++q)
#pragma unroll
        for (int m = 0; m < 2; ++m)
#pragma unroll
            for (int n = 0; n < 4; ++n) {
                const int row0 = rowBase + (q * 4 + wr * 2 + m) * 16 + crl;
                float* cp = C + (size_t)row0 * Nsz + ccol0 + n * 16;
#pragma unroll
                for (int j = 0; j < 4; ++j)
                    cp[(size_t)j * Nsz] = acc[q * 2 + m][n][j];
            }
}

// ---------------- fallback (ws too small): exact fp32, slow but correct ----------------
__global__ void gemm_naive(const float* __restrict__ x, const int* __restrict__ t,
                           const float* __restrict__ s, float* __restrict__ C) {
    size_t o = (size_t)blockIdx.x * blockDim.x + threadIdx.x;
    if (o >= (size_t)Msz * Nsz) return;
    int m = (int)(o / Nsz), n = (int)(o % Nsz);
    float acc = 0.f;
    for (int g = 0; g < Ksz / 128; ++g) {
        float sc = s[n * (Ksz / 128) + g];
        float p = 0.f;
        const float* xp = x + (size_t)m * Ksz + g * 128;
        const int* tp = t + (size_t)n * Ksz + g * 128;
        for (int k = 0; k < 128; ++k) p += xp[k] * (float)tp[k];
        acc += sc * p;
    }
    C[o] = acc;
}

extern "C" void kernel_launch(void* const* d_in, const int* in_sizes, int n_in,
                              void* d_out, int out_size, void* d_ws, size_t ws_size,
                              hipStream_t stream) {
    const float* x      = (const float*)d_in[0];
    const int*   tern   = (const int*)d_in[1];
    const float* scales = (const float*)d_in[2];
    float* out = (float*)d_out;

    const size_t aBytes = (size_t)Msz * Ksz * 2; // 64 MiB
    const size_t bBytes = (size_t)Nsz * Ksz * 2; // 32 MiB

    if (ws_size >= aBytes + bBytes) {
        unsigned short* Abf = (unsigned short*)d_ws;
        unsigned short* Bbf = (unsigned short*)((char*)d_ws + aBytes);
        prep<<<3072, 256, 0, stream>>>(x, tern, scales, Abf, Bbf);
        dim3 grid(Nsz / 256, Msz / 256);
        gemm_8p<<<grid, 512, 0, stream>>>(Abf, Bbf, out);
    } else {
        gemm_naive<<<(int)(((size_t)Msz * Nsz + 255) / 256), 256, 0, stream>>>(x, tern, scales, out);
    }
}